// Round 2
// baseline (360.288 us; speedup 1.0000x reference)
//
#include <hip/hip_runtime.h>
#include <hip/hip_bf16.h>
#include <cstdint>
#include <cstddef>

// Problem constants (from reference)
#define XL      432
#define YL      496
#define PLANE   (XL * YL)      // 214272
#define BSZ     4
#define NPIL    80000
#define NPTS    32
#define OUTC    64

__device__ __forceinline__ float bf2f(uint16_t u) { return __uint_as_float(((uint32_t)u) << 16); }
__device__ __forceinline__ uint16_t f2bf(float f) {
    uint32_t x = __float_as_uint(f);
    x += 0x7fffu + ((x >> 16) & 1u);   // RTNE
    return (uint16_t)(x >> 16);
}
// scalar load, dtype selected at runtime (uniform)
__device__ __forceinline__ float ld(const void* p, int i, bool bf) {
    return bf ? bf2f(((const uint16_t*)p)[i]) : ((const float*)p)[i];
}
// load one point (x,y,z,i) at flat point-index idx
__device__ __forceinline__ float4 load_pt(const void* pillars, size_t idx, bool bf) {
    if (bf) {
        uint2 d = ((const uint2*)pillars)[idx];
        return make_float4(__uint_as_float(d.x << 16), __uint_as_float(d.x & 0xffff0000u),
                           __uint_as_float(d.y << 16), __uint_as_float(d.y & 0xffff0000u));
    }
    return ((const float4*)pillars)[idx];
}

// Dtype probe: low 16 bits of each 32b word as bf16. bf16 data -> real normal
// samples (~100% in [1e-20,1e4]); f32 data -> mantissa bits, uniform exponent
// (~31% plausible). 1024 samples, threshold 60%.
__global__ void detect_dtype_kernel(const uint32_t* __restrict__ pr, int* __restrict__ flag) {
    const int lane = threadIdx.x;   // 64 threads
    int cnt = 0;
    #pragma unroll
    for (int i = 0; i < 16; ++i) {
        uint32_t wd = pr[lane * 16 + i];
        float a = fabsf(__uint_as_float((wd & 0xffffu) << 16));
        cnt += (a > 1e-20f && a < 1e4f) ? 1 : 0;
    }
    #pragma unroll
    for (int m = 1; m <= 32; m <<= 1) cnt += __shfl_xor(cnt, m, 64);
    if (lane == 0) flag[0] = (cnt > 614) ? 1 : 0;   // 1 = bf16, 0 = f32
}

// Kernel 1: one wave per pillar, lane = output channel. BN folded into conv,
// 9-dot collapsed to 4-FMA affine form; pooled kept in f32 internally.
__global__ __launch_bounds__(256) void pillar_feat_kernel(
    const void* __restrict__ pillars,   // (P, 32, 4) f32 or bf16
    const int*  __restrict__ npoints,   // (P,)
    const int*  __restrict__ coors,     // (P, 4): b, x, y, 0
    const void* __restrict__ conv_w,    // (64, 9)
    const void* __restrict__ gamma,
    const void* __restrict__ beta,
    const void* __restrict__ mean,
    const void* __restrict__ var,
    const int*  __restrict__ flag,
    float*      __restrict__ pooled,    // f32 (P, 64)
    int*        __restrict__ map)       // (BSZ, YL, XL), pre-filled -1
{
    const bool bf  = (flag[0] != 0);
    const int lane = threadIdx.x & 63;
    const int wave = threadIdx.x >> 6;
    const int p    = blockIdx.x * 4 + wave;   // 20000 blocks * 4 waves = 80000

    // per-channel constants: fold BN into conv weights
    const float g  = ld(gamma, lane, bf);
    const float bt = ld(beta,  lane, bf);
    const float mn = ld(mean,  lane, bf);
    const float vr = ld(var,   lane, bf);
    const float scale  = g / sqrtf(vr + 1e-3f);
    const float bprime = bt - mn * scale;

    float w[9];
    #pragma unroll
    for (int k = 0; k < 9; ++k) w[k] = ld(conv_w, lane * 9 + k, bf) * scale;

    // features affine in raw point (x,y,z,i): 9-dot -> 4-dot + pillar constant
    const float ax = w[0] + w[4] + w[7];
    const float ay = w[1] + w[5] + w[8];
    const float az = w[2] + w[6];
    const float ai = w[3];

    const int np = npoints[p];
    const int cb = coors[p * 4 + 0];
    const int cx = coors[p * 4 + 1];
    const int cy = coors[p * 4 + 2];

    const size_t base = (size_t)p * NPTS;

    // unmasked sum of x,y,z over all 32 points (reference sums raw pillars);
    // lanes 0-31 and 32-63 mirror-load, xor-butterfly 1..16 gives full sum.
    float4 d = load_pt(pillars, base + (lane & 31), bf);
    float sx = d.x, sy = d.y, sz = d.z;
    #pragma unroll
    for (int m = 1; m <= 16; m <<= 1) {
        sx += __shfl_xor(sx, m, 64);
        sy += __shfl_xor(sy, m, 64);
        sz += __shfl_xor(sz, m, 64);
    }
    const float inv = 1.0f / (float)np;
    const float mx = sx * inv, my = sy * inv, mz = sz * inv;

    const float gx = (float)cx * 0.16f + 0.08f;
    const float gy = (float)cy * 0.16f + (0.08f - 39.68f);
    const float Kc = bprime - (mx * w[4] + my * w[5] + mz * w[6]) - gx * w[7] - gy * w[8];

    // masked rows contribute b' pre-relu; relu∘max == max∘relu
    float m = (np < NPTS) ? bprime : -3.0e38f;
    if (bf) {
        const uint2* pp = (const uint2*)pillars + base;
        for (int n = 0; n < np; ++n) {
            uint2 q = pp[n];                      // wave-uniform broadcast load
            float v = Kc;
            v = fmaf(__uint_as_float(q.x << 16),          ax, v);
            v = fmaf(__uint_as_float(q.x & 0xffff0000u),  ay, v);
            v = fmaf(__uint_as_float(q.y << 16),          az, v);
            v = fmaf(__uint_as_float(q.y & 0xffff0000u),  ai, v);
            m = fmaxf(m, v);
        }
    } else {
        const float4* pp = (const float4*)pillars + base;
        for (int n = 0; n < np; ++n) {
            float4 q = pp[n];
            float v = Kc;
            v = fmaf(q.x, ax, v);
            v = fmaf(q.y, ay, v);
            v = fmaf(q.z, az, v);
            v = fmaf(q.w, ai, v);
            m = fmaxf(m, v);
        }
    }
    m = fmaxf(m, 0.0f);

    pooled[(size_t)p * OUTC + lane] = m;
    if (lane == 0) map[cb * PLANE + cy * XL + cx] = p;
}

// Kernel 2: stream output canvas (b, c, y, x) in layout order, gather pooled
// through the index map. Coalesced 16B (f32) / 8B (bf16) stores.
__global__ __launch_bounds__(256) void scatter_canvas_kernel(
    const int*   __restrict__ map,
    const float* __restrict__ pooled,
    const int*   __restrict__ flag,
    void*        __restrict__ out)
{
    const bool bf = (flag[0] != 0);
    const int bc = blockIdx.y;            // b*64 + c
    const int c  = bc & 63;
    const int b  = bc >> 6;
    const int e  = (blockIdx.x * 256 + threadIdx.x) * 4;
    if (e >= PLANE) return;

    int4 m4 = *(const int4*)(map + b * PLANE + e);
    float v0 = (m4.x >= 0) ? pooled[(size_t)m4.x * OUTC + c] : 0.0f;
    float v1 = (m4.y >= 0) ? pooled[(size_t)m4.y * OUTC + c] : 0.0f;
    float v2 = (m4.z >= 0) ? pooled[(size_t)m4.z * OUTC + c] : 0.0f;
    float v3 = (m4.w >= 0) ? pooled[(size_t)m4.w * OUTC + c] : 0.0f;

    const size_t o = (size_t)bc * PLANE + e;
    if (bf) {
        ushort4 s;
        s.x = f2bf(v0); s.y = f2bf(v1); s.z = f2bf(v2); s.w = f2bf(v3);
        *(ushort4*)((uint16_t*)out + o) = s;
    } else {
        *(float4*)((float*)out + o) = make_float4(v0, v1, v2, v3);
    }
}

extern "C" void kernel_launch(void* const* d_in, const int* in_sizes, int n_in,
                              void* d_out, int out_size, void* d_ws, size_t ws_size,
                              hipStream_t stream) {
    (void)in_sizes; (void)n_in; (void)out_size; (void)ws_size;

    // ws layout: [flag 16B][map: BSZ*PLANE int][pooled: NPIL*OUTC f32] ~ 24 MB
    int*   flag   = (int*)d_ws;
    int*   map    = (int*)((char*)d_ws + 16);
    float* pooled = (float*)((char*)d_ws + 16 + sizeof(int) * (size_t)BSZ * PLANE);

    hipMemsetAsync(map, 0xFF, sizeof(int) * (size_t)BSZ * PLANE, stream);
    detect_dtype_kernel<<<1, 64, 0, stream>>>((const uint32_t*)d_in[0], flag);

    pillar_feat_kernel<<<NPIL / 4, 256, 0, stream>>>(
        d_in[0], (const int*)d_in[1], (const int*)d_in[2],
        d_in[3], d_in[4], d_in[5], d_in[6], d_in[7],
        flag, pooled, map);

    dim3 g2((PLANE / 4 + 255) / 256, BSZ * OUTC);
    scatter_canvas_kernel<<<g2, 256, 0, stream>>>(map, pooled, flag, (uint16_t*)d_out);
}

// Round 3
// 349.554 us; speedup vs baseline: 1.0307x; 1.0307x over previous
//
#include <hip/hip_runtime.h>
#include <cstdint>
#include <cstddef>

// Problem constants (from reference)
#define XL      432
#define YL      496
#define PLANE   (XL * YL)      // 214272 (y-major: idx = y*XL + x)
#define BSZ     4
#define NPIL    80000
#define NPTS    32
#define OUTC    64

__device__ __forceinline__ float bf2f(uint16_t u) { return __uint_as_float(((uint32_t)u) << 16); }
__device__ __forceinline__ uint16_t f2bf(float f) {
    uint32_t x = __float_as_uint(f);
    x += 0x7fffu + ((x >> 16) & 1u);   // RTNE
    return (uint16_t)(x >> 16);
}
__device__ __forceinline__ float ld(const void* p, int i, bool bf) {
    return bf ? bf2f(((const uint16_t*)p)[i]) : ((const float*)p)[i];
}

// In-wave dtype probe on the first 64 words of `pillars` (wave-uniform data,
// L2-broadcast). bf16 data: low-half-as-bf16 is a real N(0,1) sample
// (plausible ~64/64). f32 data: low half is mantissa bits -> uniform exponent
// (plausible ~20/64, sigma 3.7). Threshold 40 is >5 sigma from both.
__device__ __forceinline__ bool probe_bf16(const void* pillars) {
    const int lane = threadIdx.x & 63;
    uint32_t w = ((const uint32_t*)pillars)[lane];
    float a = fabsf(__uint_as_float(w << 16));
    bool pl = (a > 1e-20f) && (a < 1e4f);
    return __popcll(__ballot(pl)) >= 40;
}

// Kernel 1: one wave per pillar, lane = output channel. BN folded into conv
// weights; the 9 affine features collapse to a 4-FMA dot + per-pillar const.
// Point loop unrolled x2 with dual max accumulators (breaks fmax serial chain).
__global__ __launch_bounds__(256) void pillar_feat_kernel(
    const void* __restrict__ pillars,   // (P, 32, 4) bf16 or f32
    const int*  __restrict__ npoints,   // (P,)
    const int*  __restrict__ coors,     // (P, 4): b, x, y, 0
    const void* __restrict__ conv_w,    // (64, 9)
    const void* __restrict__ gamma,
    const void* __restrict__ beta,
    const void* __restrict__ mean,
    const void* __restrict__ var,
    float*      __restrict__ pooled,    // f32 (P, 64)
    int*        __restrict__ map)       // (BSZ, PLANE), pre-filled -1
{
    const bool bf  = probe_bf16(pillars);
    const int lane = threadIdx.x & 63;
    const int wave = threadIdx.x >> 6;
    const int p    = blockIdx.x * 4 + wave;   // 20000 blocks * 4 waves = 80000

    // per-channel constants: fold BN into conv weights
    const float scale  = ld(gamma, lane, bf) * __frsqrt_rn(ld(var, lane, bf) + 1e-3f);
    const float bprime = ld(beta, lane, bf) - ld(mean, lane, bf) * scale;

    float w[9];
    #pragma unroll
    for (int k = 0; k < 9; ++k) w[k] = ld(conv_w, lane * 9 + k, bf) * scale;

    // features affine in raw point (x,y,z,i): 9-dot -> 4-dot + pillar constant
    const float ax = w[0] + w[4] + w[7];
    const float ay = w[1] + w[5] + w[8];
    const float az = w[2] + w[6];
    const float ai = w[3];

    const int np = npoints[p];
    const int cb = coors[p * 4 + 0];
    const int cx = coors[p * 4 + 1];
    const int cy = coors[p * 4 + 2];

    const size_t base = (size_t)p * NPTS;

    // unmasked sum of x,y,z over all 32 points; lanes 0-31 / 32-63 mirror-load,
    // xor-butterfly 1..16 leaves the full sum in every lane.
    float sx, sy, sz;
    if (bf) {
        uint2 d = ((const uint2*)pillars)[base + (lane & 31)];
        sx = __uint_as_float(d.x << 16);
        sy = __uint_as_float(d.x & 0xffff0000u);
        sz = __uint_as_float(d.y << 16);
    } else {
        float4 d = ((const float4*)pillars)[base + (lane & 31)];
        sx = d.x; sy = d.y; sz = d.z;
    }
    #pragma unroll
    for (int m = 1; m <= 16; m <<= 1) {
        sx += __shfl_xor(sx, m, 64);
        sy += __shfl_xor(sy, m, 64);
        sz += __shfl_xor(sz, m, 64);
    }
    const float inv = 1.0f / (float)np;
    const float gx = (float)cx * 0.16f + 0.08f;
    const float gy = (float)cy * 0.16f + (0.08f - 39.68f);
    const float Kc = bprime - inv * (sx * w[4] + sy * w[5] + sz * w[6])
                            - gx * w[7] - gy * w[8];

    // masked rows contribute b' pre-relu; relu(max) == max(relu)
    float m0 = (np < NPTS) ? bprime : -3.0e38f;
    float m1 = -3.0e38f;
    int n = 0;
    if (bf) {
        const uint2* pp = (const uint2*)pillars + base;
        for (; n + 2 <= np; n += 2) {
            uint2 qa = pp[n];
            uint2 qb = pp[n + 1];
            float va = Kc, vb = Kc;
            va = fmaf(__uint_as_float(qa.x << 16),         ax, va);
            va = fmaf(__uint_as_float(qa.x & 0xffff0000u), ay, va);
            va = fmaf(__uint_as_float(qa.y << 16),         az, va);
            va = fmaf(__uint_as_float(qa.y & 0xffff0000u), ai, va);
            vb = fmaf(__uint_as_float(qb.x << 16),         ax, vb);
            vb = fmaf(__uint_as_float(qb.x & 0xffff0000u), ay, vb);
            vb = fmaf(__uint_as_float(qb.y << 16),         az, vb);
            vb = fmaf(__uint_as_float(qb.y & 0xffff0000u), ai, vb);
            m0 = fmaxf(m0, va);
            m1 = fmaxf(m1, vb);
        }
        if (n < np) {
            uint2 qa = pp[n];
            float va = Kc;
            va = fmaf(__uint_as_float(qa.x << 16),         ax, va);
            va = fmaf(__uint_as_float(qa.x & 0xffff0000u), ay, va);
            va = fmaf(__uint_as_float(qa.y << 16),         az, va);
            va = fmaf(__uint_as_float(qa.y & 0xffff0000u), ai, va);
            m0 = fmaxf(m0, va);
        }
    } else {
        const float4* pp = (const float4*)pillars + base;
        for (; n + 2 <= np; n += 2) {
            float4 qa = pp[n];
            float4 qb = pp[n + 1];
            float va = Kc, vb = Kc;
            va = fmaf(qa.x, ax, va); va = fmaf(qa.y, ay, va);
            va = fmaf(qa.z, az, va); va = fmaf(qa.w, ai, va);
            vb = fmaf(qb.x, ax, vb); vb = fmaf(qb.y, ay, vb);
            vb = fmaf(qb.z, az, vb); vb = fmaf(qb.w, ai, vb);
            m0 = fmaxf(m0, va);
            m1 = fmaxf(m1, vb);
        }
        if (n < np) {
            float4 qa = pp[n];
            float va = Kc;
            va = fmaf(qa.x, ax, va); va = fmaf(qa.y, ay, va);
            va = fmaf(qa.z, az, va); va = fmaf(qa.w, ai, va);
            m0 = fmaxf(m0, va);
        }
    }
    float m = fmaxf(fmaxf(m0, m1), 0.0f);

    pooled[(size_t)p * OUTC + lane] = m;   // 64 lanes x 4B = 256B coalesced
    if (lane == 0) map[cb * PLANE + cy * XL + cx] = p;
}

// Kernel 2: stream output (b, c, y, x) in layout order. blockIdx.y = (b, cg)
// where cg picks 8 channels; each thread covers 4 cells x 8 channels, so one
// 32B contiguous load per cell fetches all 8 channels of that pillar row.
__global__ __launch_bounds__(256) void scatter_canvas_kernel(
    const void*  __restrict__ pillars,   // only for dtype probe
    const int*   __restrict__ map,
    const float* __restrict__ pooled,
    void*        __restrict__ out)
{
    const bool bf = probe_bf16(pillars);
    const int by = blockIdx.y;           // b*8 + cg
    const int b  = by >> 3;
    const int cg = by & 7;               // channels cg*8 .. cg*8+7
    const int e  = (blockIdx.x * 256 + threadIdx.x) * 4;
    if (e >= PLANE) return;

    int4 m4 = *(const int4*)(map + b * PLANE + e);
    const int idx[4] = {m4.x, m4.y, m4.z, m4.w};

    float v[4][8];
    #pragma unroll
    for (int i = 0; i < 4; ++i) {
        if (idx[i] >= 0) {
            const float4* row = (const float4*)(pooled + (size_t)idx[i] * OUTC + cg * 8);
            float4 lo = row[0], hi = row[1];
            v[i][0] = lo.x; v[i][1] = lo.y; v[i][2] = lo.z; v[i][3] = lo.w;
            v[i][4] = hi.x; v[i][5] = hi.y; v[i][6] = hi.z; v[i][7] = hi.w;
        } else {
            #pragma unroll
            for (int j = 0; j < 8; ++j) v[i][j] = 0.0f;
        }
    }

    const int c0 = cg * 8;
    if (bf) {
        uint16_t* o16 = (uint16_t*)out;
        #pragma unroll
        for (int j = 0; j < 8; ++j) {
            ushort4 s;
            s.x = f2bf(v[0][j]); s.y = f2bf(v[1][j]);
            s.z = f2bf(v[2][j]); s.w = f2bf(v[3][j]);
            *(ushort4*)(o16 + (size_t)((b * OUTC + c0 + j)) * PLANE + e) = s;
        }
    } else {
        float* o32 = (float*)out;
        #pragma unroll
        for (int j = 0; j < 8; ++j) {
            *(float4*)(o32 + (size_t)((b * OUTC + c0 + j)) * PLANE + e) =
                make_float4(v[0][j], v[1][j], v[2][j], v[3][j]);
        }
    }
}

extern "C" void kernel_launch(void* const* d_in, const int* in_sizes, int n_in,
                              void* d_out, int out_size, void* d_ws, size_t ws_size,
                              hipStream_t stream) {
    (void)in_sizes; (void)n_in; (void)out_size; (void)ws_size;

    // ws layout: [map: BSZ*PLANE int = 3.27 MB][pooled: NPIL*64 f32 = 20.5 MB]
    int*   map    = (int*)d_ws;
    float* pooled = (float*)((char*)d_ws + sizeof(int) * (size_t)BSZ * PLANE);

    hipMemsetAsync(map, 0xFF, sizeof(int) * (size_t)BSZ * PLANE, stream);

    pillar_feat_kernel<<<NPIL / 4, 256, 0, stream>>>(
        d_in[0], (const int*)d_in[1], (const int*)d_in[2],
        d_in[3], d_in[4], d_in[5], d_in[6], d_in[7],
        pooled, map);

    dim3 g2((PLANE / 4 + 255) / 256, BSZ * 8);
    scatter_canvas_kernel<<<g2, 256, 0, stream>>>(d_in[0], map, pooled, d_out);
}